// Round 1
// baseline (137.730 us; speedup 1.0000x reference)
//
#include <hip/hip_runtime.h>
#include <hip/hip_bf16.h>

#define NN 8192
#define FF 256
#define NEGV -9000000000000000.0f

typedef __bf16 bf16x8 __attribute__((ext_vector_type(8)));
typedef float f32x4 __attribute__((ext_vector_type(4)));

__device__ __forceinline__ void load_lds16(const void* g, void* l) {
  auto gp = (const __attribute__((address_space(1))) void*)(uintptr_t)g;
  auto lp = (__attribute__((address_space(3))) void*)(uint32_t)(uintptr_t)l;
  __builtin_amdgcn_global_load_lds(gp, lp, 16, 0, 0);
}

// ---------------- kernel 1: gather rows of `inputs` per nbr, convert to bf16 ----------------
// A[m, :] = inputs[nbr[m,1]] for m < 8192 (x), inputs[nbr[m-8192,0]] for m >= 8192 (h)
__global__ __launch_bounds__(256) void k_gather_bf16(const float* __restrict__ inputs,
                                                     const int* __restrict__ nbr,
                                                     __hip_bfloat16* __restrict__ Abf) {
  const int gid = blockIdx.x * 256 + threadIdx.x;   // 16384*64 = 1,048,576 threads
  const int m = gid >> 6;
  const int c = (gid & 63) << 2;
  const int src = (m < NN) ? nbr[2 * m + 1] : nbr[2 * (m - NN)];
  const float4 v = *(const float4*)(inputs + (size_t)src * FF + c);
  union { __hip_bfloat16 h[4]; uint2 u; } t;
  t.h[0] = __float2bfloat16(v.x);
  t.h[1] = __float2bfloat16(v.y);
  t.h[2] = __float2bfloat16(v.z);
  t.h[3] = __float2bfloat16(v.w);
  *(uint2*)(Abf + (size_t)m * FF + c) = t.u;
}

// ---------------- kernel 2: convert W_ih / W_hh to bf16, stacked [1536, 256] ----------------
__global__ __launch_bounds__(256) void k_conv_w(const float* __restrict__ Wih,
                                                const float* __restrict__ Whh,
                                                __hip_bfloat16* __restrict__ Bbf) {
  const int gid = blockIdx.x * 256 + threadIdx.x;   // 1536*64 = 98,304 threads
  const int r = gid >> 6;
  const int c = (gid & 63) << 2;
  const float* src = (r < 768) ? (Wih + (size_t)r * FF + c) : (Whh + (size_t)(r - 768) * FF + c);
  const float4 v = *(const float4*)src;
  union { __hip_bfloat16 h[4]; uint2 u; } t;
  t.h[0] = __float2bfloat16(v.x);
  t.h[1] = __float2bfloat16(v.y);
  t.h[2] = __float2bfloat16(v.z);
  t.h[3] = __float2bfloat16(v.w);
  *(uint2*)(Bbf + (size_t)r * FF + c) = t.u;
}

// ---------------- kernel 3: bf16 MFMA GEMM: C[16384,768] = A @ Bsel^T ----------------
// Rows < 8192 use W_ih block (Bbf rows 0..767), rows >= 8192 use W_hh block (768..1535).
// 128x128 tile, BK=64, 4 waves (2x2), each wave 64x64 via 4x4 mfma_f32_16x16x32_bf16.
#define BM 128
#define BN 128
#define BK 64
__global__ __launch_bounds__(256) void k_gemm(const __hip_bfloat16* __restrict__ A,
                                              const __hip_bfloat16* __restrict__ B,
                                              float* __restrict__ C) {
  __shared__ __align__(16) __hip_bfloat16 As[BM * BK];
  __shared__ __align__(16) __hip_bfloat16 Bs[BN * BK];
  const int m0 = blockIdx.y * BM;                 // 0..16256
  const int n0t = blockIdx.x * BN;                // 0..640
  const int wbase = (m0 < NN) ? 0 : 768;
  const int n0 = n0t + wbase;                     // row base in Bbf
  const int tid = threadIdx.x;
  const int w = tid >> 6, l = tid & 63;
  const int wm = w >> 1, wn = w & 1;

  f32x4 acc[4][4] = {};

  for (int k0 = 0; k0 < FF; k0 += BK) {
    // stage A and B tiles via global_load_lds (linear LDS dest, wave-uniform base + lane*16)
#pragma unroll
    for (int c = 0; c < 4; ++c) {
      const int chunk = w * 4 + c;                // 0..15, uniform per wave
      const int rrow = chunk * 8 + (l >> 3);      // 0..127
      const int kk = (l & 7) * 8;                 // 0..56
      load_lds16(A + (size_t)(m0 + rrow) * FF + k0 + kk, (char*)As + chunk * 1024);
      load_lds16(B + (size_t)(n0 + rrow) * FF + k0 + kk, (char*)Bs + chunk * 1024);
    }
    __syncthreads();
#pragma unroll
    for (int kk = 0; kk < 2; ++kk) {
      bf16x8 af[4], bfr[4];
#pragma unroll
      for (int m = 0; m < 4; ++m) {
        const int row = wm * 64 + m * 16 + (l & 15);
        const int k = kk * 32 + (l >> 4) * 8;
        af[m] = *(const bf16x8*)&As[row * BK + k];
      }
#pragma unroll
      for (int n = 0; n < 4; ++n) {
        const int col = wn * 64 + n * 16 + (l & 15);
        const int k = kk * 32 + (l >> 4) * 8;
        bfr[n] = *(const bf16x8*)&Bs[col * BK + k];
      }
#pragma unroll
      for (int m = 0; m < 4; ++m)
#pragma unroll
        for (int n = 0; n < 4; ++n)
          acc[m][n] = __builtin_amdgcn_mfma_f32_16x16x32_bf16(af[m], bfr[n], acc[m][n], 0, 0, 0);
    }
    __syncthreads();
  }
  // epilogue: C/D layout col = lane&15, row = (lane>>4)*4 + j
#pragma unroll
  for (int m = 0; m < 4; ++m) {
#pragma unroll
    for (int n = 0; n < 4; ++n) {
      const int col = n0t + wn * 64 + n * 16 + (l & 15);
      const int rbase = m0 + wm * 64 + m * 16 + (l >> 4) * 4;
#pragma unroll
      for (int j = 0; j < 4; ++j)
        C[(size_t)(rbase + j) * 768 + col] = acc[m][n][j];
    }
  }
}

// ---------------- kernel 4: GRU combine + dot with a1/a2 -> s1[i], s2[i] ----------------
__global__ __launch_bounds__(256) void k_combine(const float* __restrict__ C,
                                                 const float* __restrict__ inputs,
                                                 const int* __restrict__ nbr,
                                                 const float* __restrict__ b_ih,
                                                 const float* __restrict__ b_hh,
                                                 const float* __restrict__ a,
                                                 float* __restrict__ s1,
                                                 float* __restrict__ s2) {
  const int i = blockIdx.x;     // row 0..8191
  const int c = threadIdx.x;    // feature 0..255
  const float* Ci = C + (size_t)i * 768;
  const float* Ch = C + (size_t)(NN + i) * 768;
  const float ir = Ci[c]       + b_ih[c];
  const float iz = Ci[256 + c] + b_ih[256 + c];
  const float in_ = Ci[512 + c] + b_ih[512 + c];
  const float hr = Ch[c]       + b_hh[c];
  const float hz = Ch[256 + c] + b_hh[256 + c];
  const float hn = Ch[512 + c] + b_hh[512 + c];
  const float r = 1.f / (1.f + __expf(-(ir + hr)));
  const float z = 1.f / (1.f + __expf(-(iz + hz)));
  const float n = tanhf(in_ + r * hn);
  const float h = inputs[(size_t)nbr[2 * i] * FF + c];
  const float o = (1.f - z) * n + z * h;
  float p1 = o * a[c];
  float p2 = o * a[256 + c];
#pragma unroll
  for (int off = 32; off; off >>= 1) {
    p1 += __shfl_xor(p1, off);
    p2 += __shfl_xor(p2, off);
  }
  __shared__ float w1[4], w2[4];
  if ((c & 63) == 0) { w1[c >> 6] = p1; w2[c >> 6] = p2; }
  __syncthreads();
  if (c == 0) {
    s1[i] = w1[0] + w1[1] + w1[2] + w1[3];
    s2[i] = w2[0] + w2[1] + w2[2] + w2[3];
  }
}

// ---------------- kernel 5: masked row softmax, e-values in registers ----------------
// out[i,j] = softmax_j( adj[i,j]>0 ? lrelu(s1_i + s2_j) : NEG )
__global__ __launch_bounds__(256) void k_softmax(const int* __restrict__ adj,
                                                 const float* __restrict__ s1,
                                                 const float* __restrict__ s2,
                                                 float* __restrict__ out) {
  __shared__ __align__(16) float s2s[NN];
  __shared__ float red[8];
  const int row = blockIdx.x;
  const int t = threadIdx.x;
#pragma unroll
  for (int k = 0; k < 8; ++k) {
    const int v = k * 256 + t;
    *(float4*)(s2s + v * 4) = *(const float4*)(s2 + v * 4);
  }
  const float s1v = s1[row];
  __syncthreads();
  const int4* adjv = (const int4*)(adj + (size_t)row * NN);
  float e[32];
  float tmax = -3.4e38f;
#pragma unroll
  for (int k = 0; k < 8; ++k) {
    const int v = k * 256 + t;
    const int4 a4 = adjv[v];
    const float4 sv = *(const float4*)(s2s + v * 4);
    float x0 = s1v + sv.x; x0 = (x0 > 0.f) ? x0 : 0.2f * x0;
    float x1 = s1v + sv.y; x1 = (x1 > 0.f) ? x1 : 0.2f * x1;
    float x2 = s1v + sv.z; x2 = (x2 > 0.f) ? x2 : 0.2f * x2;
    float x3 = s1v + sv.w; x3 = (x3 > 0.f) ? x3 : 0.2f * x3;
    e[4 * k + 0] = (a4.x > 0) ? x0 : NEGV;
    e[4 * k + 1] = (a4.y > 0) ? x1 : NEGV;
    e[4 * k + 2] = (a4.z > 0) ? x2 : NEGV;
    e[4 * k + 3] = (a4.w > 0) ? x3 : NEGV;
    tmax = fmaxf(tmax, fmaxf(fmaxf(e[4 * k], e[4 * k + 1]), fmaxf(e[4 * k + 2], e[4 * k + 3])));
  }
#pragma unroll
  for (int off = 32; off; off >>= 1) tmax = fmaxf(tmax, __shfl_xor(tmax, off));
  if ((t & 63) == 0) red[t >> 6] = tmax;
  __syncthreads();
  const float rmax = fmaxf(fmaxf(red[0], red[1]), fmaxf(red[2], red[3]));
  float tsum = 0.f;
#pragma unroll
  for (int i = 0; i < 32; ++i) { e[i] = __expf(e[i] - rmax); tsum += e[i]; }
#pragma unroll
  for (int off = 32; off; off >>= 1) tsum += __shfl_xor(tsum, off);
  if ((t & 63) == 0) red[4 + (t >> 6)] = tsum;
  __syncthreads();
  const float inv = 1.f / (red[4] + red[5] + red[6] + red[7]);
  float* orow = out + (size_t)row * NN;
#pragma unroll
  for (int k = 0; k < 8; ++k) {
    const int v = k * 256 + t;
    float4 o;
    o.x = e[4 * k + 0] * inv;
    o.y = e[4 * k + 1] * inv;
    o.z = e[4 * k + 2] * inv;
    o.w = e[4 * k + 3] * inv;
    *(float4*)(orow + v * 4) = o;
  }
}

extern "C" void kernel_launch(void* const* d_in, const int* in_sizes, int n_in,
                              void* d_out, int out_size, void* d_ws, size_t ws_size,
                              hipStream_t stream) {
  const float* inputs = (const float*)d_in[0];
  const float* W_ih   = (const float*)d_in[1];
  const float* W_hh   = (const float*)d_in[2];
  const float* b_ih   = (const float*)d_in[3];
  const float* b_hh   = (const float*)d_in[4];
  const float* a      = (const float*)d_in[5];
  const int*   nbr    = (const int*)d_in[6];
  const int*   adj    = (const int*)d_in[7];
  float* out = (float*)d_out;

  // Scratch inside d_out (fully overwritten by k_softmax at the end):
  //   [0, 48MB)   : C = gi/gh  f32 [16384, 768]
  //   [64MB, 72MB): Abf bf16 [16384, 256]
  //   [80MB, ...) : Bbf bf16 [1536, 256]
  float* Cbuf = out;
  __hip_bfloat16* Abf = (__hip_bfloat16*)((char*)d_out + (64u << 20));
  __hip_bfloat16* Bbf = (__hip_bfloat16*)((char*)d_out + (80u << 20));
  float* s1 = (float*)d_ws;        // 32 KB
  float* s2 = s1 + NN;             // 32 KB

  k_gather_bf16<<<4096, 256, 0, stream>>>(inputs, nbr, Abf);
  k_conv_w<<<384, 256, 0, stream>>>(W_ih, W_hh, Bbf);
  k_gemm<<<dim3(6, 128), 256, 0, stream>>>(Abf, Bbf, Cbuf);
  k_combine<<<NN, 256, 0, stream>>>(Cbuf, inputs, nbr, b_ih, b_hh, a, s1, s2);
  k_softmax<<<NN, 256, 0, stream>>>(adj, s1, s2, out);
}